// Round 11
// baseline (569.395 us; speedup 1.0000x reference)
//
#include <hip/hip_runtime.h>
#include <hip/hip_bf16.h>

// out[B,S,O] = A[B,S,I] @ W[O,I]^T * scales[O] + bias[O]
// M = 16384, N = 4096, K = 4096. Output fp32.
// i8 path: A per-row quant (amax/127), W exact i8; mfma_i32_16x16x64_i8;
// dequant epilogue acc * (ascale[m]*scales[n]) + bias[n].
// R11 vs R10: ONE fix — P4 computes QUAD(1,0) with the OLD b0 BEFORE
// ISSUE_B(t+1) overwrites b0/b1 (R10 overwrote first in program order =>
// deterministic wrong tile). Fence ledger unchanged and re-audited.
#define M_TOTAL 16384
#define N_TOTAL 4096
#define K_TOTAL 4096
#define NT (K_TOTAL / 128)  // 32 K-tiles of BK=128 (i8)

typedef __attribute__((ext_vector_type(4))) int i32x4;
typedef __attribute__((ext_vector_type(4))) float f32x4;

__device__ __forceinline__ unsigned pack4(int a, int b, int c, int d) {
  return (a & 0xFF) | ((b & 0xFF) << 8) | ((c & 0xFF) << 16) | ((d & 0xFF) << 24);
}

// ---- A quantization: one block per row; lane-contiguous 16B loads ----
__global__ __launch_bounds__(256) void quant_a(const float* __restrict__ A,
                                               unsigned* __restrict__ Aq,
                                               float* __restrict__ ascale) {
  const int row = blockIdx.x;
  const int tid = threadIdx.x;
  const float4* src = reinterpret_cast<const float4*>(A + (size_t)row * K_TOTAL);
  float4 v[4];
#pragma unroll
  for (int c = 0; c < 4; ++c) v[c] = src[tid + 256 * c];  // lane-contig 16B
  float amax = 0.0f;
#pragma unroll
  for (int c = 0; c < 4; ++c) {
    amax = fmaxf(amax, fmaxf(fmaxf(fabsf(v[c].x), fabsf(v[c].y)),
                             fmaxf(fabsf(v[c].z), fabsf(v[c].w))));
  }
#pragma unroll
  for (int off = 32; off > 0; off >>= 1) amax = fmaxf(amax, __shfl_xor(amax, off, 64));
  __shared__ float wmax[4];
  if ((tid & 63) == 0) wmax[tid >> 6] = amax;
  __syncthreads();
  amax = fmaxf(fmaxf(wmax[0], wmax[1]), fmaxf(wmax[2], wmax[3]));
  amax = fmaxf(amax, 1e-20f);
  const float rs = 127.0f / amax;
  if (tid == 0) ascale[row] = amax * (1.0f / 127.0f);

  unsigned* dst = Aq + (size_t)row * (K_TOTAL / 4);
#pragma unroll
  for (int c = 0; c < 4; ++c) {
    int q[4];
    float f[4] = {v[c].x, v[c].y, v[c].z, v[c].w};
#pragma unroll
    for (int i = 0; i < 4; ++i) {
      int t = (int)rintf(f[i] * rs);
      q[i] = t < -127 ? -127 : (t > 127 ? 127 : t);
    }
    dst[tid + 256 * c] = pack4(q[0], q[1], q[2], q[3]);  // lane-contig 4B
  }
}

// ---- W int32 -> int8: one int4 -> one u32 per thread, fully coalesced ----
__global__ void cvt_w_i8(const int* __restrict__ W, unsigned* __restrict__ Wq, int n4) {
  const int stride = gridDim.x * blockDim.x;
  for (int i = blockIdx.x * blockDim.x + threadIdx.x; i < n4; i += stride) {
    int4 v = reinterpret_cast<const int4*>(W)[i];
    Wq[i] = pack4(v.x, v.y, v.z, v.w);
  }
}

// ======== 256x256 i8 GEMM — A via LDS (proven skeleton), B via regs ========
#define GLOAD_LDS16(gp, lp)                                                \
  __builtin_amdgcn_global_load_lds(                                        \
      (const __attribute__((address_space(1))) void*)(gp),                 \
      (__attribute__((address_space(3))) void*)(lp), 16, 0, 0)

#define BAR() asm volatile("s_barrier" ::: "memory")
#define VM(n) asm volatile("s_waitcnt vmcnt(" #n ")" ::: "memory")

// LDS map (65536 B): buf b at b*32768: A_h0 [0,16K) A_h1 [16K,32K).
// Half-tile = 128 rows x 128 i8 cols, row stride 128 B.
// Swizzle: (r,c) at byte r*128 + (c ^ ((r&7)<<4)) (involution, 16B blocks).
// gload_lds writes linearly; GLOBAL source pre-inverse-swizzled (rule #21).
// vmcnt ledger (per-wave, A-stages + B-reg loads; compiler waits cover the
// b-register uses at P1/P2, which only ever drain OLDER B(t) entries):
//   prologue: A(0)x4 + B(0)x8 -> VM(8) drains A(0) exactly.
//   tile t at P4 fence: queue = A(t+1)x4 (P1/P2) + B(t+1)x8 (P4) = 12
//   -> VM(8) drains exactly A(t+1)x4. Fence BEFORE barrier; reads after.

__global__ __launch_bounds__(512, 2) void w8a16_gemm_i8(
    const signed char* __restrict__ A,   // [M][K] i8
    const signed char* __restrict__ Bt,  // [N][K] i8
    const float* __restrict__ ascale,    // [M] dequant scale for A rows
    const float* __restrict__ scales, const float* __restrict__ bias,
    float* __restrict__ C) {
  __shared__ alignas(16) unsigned char lds[65536];

  const int tid = threadIdx.x;
  const int w = tid >> 6, l = tid & 63;
  const int wr = w >> 2, wc = w & 3;  // 2x4 wave grid; per-wave 128x64 output

  // XCD-aware bijective swizzle (nwg=1024, 8 XCDs): per-XCD bn-sweep keeps
  // the A-panel L2-hot while B streams from L2/L3.
  const int bid = blockIdx.x;
  const int swz = ((bid & 7) << 7) + (bid >> 3);
  const int bn = swz & 15, bm = swz >> 4;

  // --- A staging (pre-inverse-swizzled global source) ---
  const int rowq = tid >> 3;                   // w*8 + (l>>3), 0..63
  const int colb = ((l & 7) ^ (l >> 3)) << 4;  // col byte block
  const signed char* pA = A + (size_t)(bm * 256 + rowq) * K_TOTAL + colb;
  unsigned char* const ldsp = lds;
  const int woff = w << 10;

#define SDA(b_, h_) (ldsp + (b_) * 32768 + (h_) * 16384 + woff)
#define STAGE_A(b_, h_, t_)                                                    \
  do {                                                                         \
    GLOAD_LDS16(pA + (size_t)((h_) * 128) * K_TOTAL + (t_) * 128, SDA(b_, h_));\
    GLOAD_LDS16(pA + (size_t)((h_) * 128 + 64) * K_TOTAL + (t_) * 128,         \
                SDA(b_, h_) + 8192);                                           \
  } while (0)

  // --- A fragment reads (swizzled LDS), same pattern as R7 ---
  const int arow = ((l & 15) << 7) + ((((l >> 4) ^ (l & 7)) & 7) << 4);

  // --- B fragment loads: per-lane global 16B. Row = output col; k contiguous.
  //     frag (nh, fn, kk): row = bn*256 + wc*64 + nh*32 + fn*16 + (l&15),
  //     k = t*128 + kk*64 + (l>>4)*16.
  const signed char* pBg =
      Bt + (size_t)(bn * 256 + wc * 64 + (l & 15)) * K_TOTAL + ((l >> 4) << 4);

  i32x4 af[8];        // 4 m-frags x 2 kk (current m-half)
  i32x4 b0[4], b1[4]; // n-half fragment sets [fn*2+kk]
  i32x4 acc[8][4] = {{}};

#define RD_A(mh_)                                                             \
  do {                                                                        \
    const unsigned char* Ab_ = ldsp + bsel * 32768 + wr * 16384;              \
    _Pragma("unroll") for (int fm = 0; fm < 4; ++fm)                          \
        _Pragma("unroll") for (int kk = 0; kk < 2; ++kk)                      \
            af[fm * 2 + kk] = *(const i32x4*)(Ab_ + ((mh_) * 4 + fm) * 2048 + \
                                              (arow ^ (kk << 6)));            \
  } while (0)
#define ISSUE_B(t_)                                                           \
  do {                                                                        \
    _Pragma("unroll") for (int fn = 0; fn < 2; ++fn)                          \
        _Pragma("unroll") for (int kk = 0; kk < 2; ++kk) {                    \
      b0[fn * 2 + kk] = *(const i32x4*)(pBg + (size_t)(fn * 16) * K_TOTAL +   \
                                        (t_) * 128 + kk * 64);                \
      b1[fn * 2 + kk] = *(const i32x4*)(pBg + (size_t)(32 + fn * 16) *        \
                                            K_TOTAL + (t_) * 128 + kk * 64);  \
    }                                                                         \
  } while (0)
#define QUAD(mh_, nh_, BF_)                                                   \
  do {                                                                        \
    __builtin_amdgcn_s_setprio(1);                                            \
    _Pragma("unroll") for (int m = 0; m < 4; ++m)                             \
        _Pragma("unroll") for (int n = 0; n < 2; ++n)                         \
            _Pragma("unroll") for (int kk = 0; kk < 2; ++kk)                  \
                acc[(mh_) * 4 + m][(nh_) * 2 + n] =                           \
                    __builtin_amdgcn_mfma_i32_16x16x64_i8(                    \
                        af[m * 2 + kk], BF_[n * 2 + kk],                      \
                        acc[(mh_) * 4 + m][(nh_) * 2 + n], 0, 0, 0);          \
    __builtin_amdgcn_s_setprio(0);                                            \
  } while (0)

  // --- prologue: A(0) staged + B(0) issued; VM(8) drains A(0) exactly ---
  STAGE_A(0, 0, 0); STAGE_A(0, 1, 0);
  ISSUE_B(0);
  VM(8);
  BAR();

  // --- main loop: proven 2-barrier-per-phase structure, A-only staging ---
  for (int t = 0; t < NT; ++t) {
    const int bsel = t & 1;
    // P1: read A h0 (cur); stage Ah0(t+1)->nxt; compute (0,0) with b0(t)
    RD_A(0);
    if (t + 1 < NT) STAGE_A(bsel ^ 1, 0, t + 1);
    BAR();
    QUAD(0, 0, b0);
    BAR();
    // P2: stage Ah1(t+1)->nxt; compute (0,1) with b1(t)
    if (t + 1 < NT) STAGE_A(bsel ^ 1, 1, t + 1);
    BAR();
    QUAD(0, 1, b1);
    BAR();
    // P3: read A h1 (cur); compute (1,1) with b1(t)
    RD_A(1);
    BAR();
    QUAD(1, 1, b1);
    BAR();
    // P4: compute (1,0) with OLD b0(t) FIRST, then prefetch B(t+1) into
    //     b0/b1 (wave-private regs), then fence A(t+1) before the barrier.
    BAR();
    QUAD(1, 0, b0);
    if (t + 1 < NT) ISSUE_B(t + 1);
    if (t < NT - 1) { VM(8); }
    BAR();
  }

  // --- epilogue: C/D col=lane&15, row=(lane>>4)*4+reg (dtype-independent);
  //     dequant acc * (ascale[row]*scales[col]) + bias ---
  const int row0 = bm * 256 + wr * 128 + ((l >> 4) << 2);
  const int col0 = bn * 256 + wc * 64 + (l & 15);
#pragma unroll
  for (int fn = 0; fn < 4; ++fn) {
    const int col = col0 + fn * 16;
    const float sc = scales[col];
    const float bi = bias[col];
#pragma unroll
    for (int fm = 0; fm < 8; ++fm) {
      const int r = row0 + fm * 16;
      float* cp = C + (size_t)r * N_TOTAL + col;
#pragma unroll
      for (int j = 0; j < 4; ++j)
        cp[(size_t)j * N_TOTAL] = fmaf((float)acc[fm][fn][j], ascale[r + j] * sc, bi);
    }
  }
}

// ---- guarded fallback (only if d_ws too small) ----
__global__ void naive_gemm(const float* __restrict__ A, const int* __restrict__ W,
                           const float* __restrict__ scales, const float* __restrict__ bias,
                           float* __restrict__ C) {
  size_t idx = (size_t)blockIdx.x * blockDim.x + threadIdx.x;
  if (idx >= (size_t)M_TOTAL * N_TOTAL) return;
  const int n = (int)(idx % N_TOTAL);
  const size_t m = idx / N_TOTAL;
  const float* a = A + m * (size_t)K_TOTAL;
  const int* w = W + (size_t)n * K_TOTAL;
  float s = 0.f;
  for (int k = 0; k < K_TOTAL; ++k) s = fmaf(a[k], (float)w[k], s);
  C[idx] = fmaf(s, scales[n], bias[n]);
}

extern "C" void kernel_launch(void* const* d_in, const int* in_sizes, int n_in,
                              void* d_out, int out_size, void* d_ws, size_t ws_size,
                              hipStream_t stream) {
  const float* A = (const float*)d_in[0];
  const int* W = (const int*)d_in[1];
  const float* scales = (const float*)d_in[2];
  const float* bias = (const float*)d_in[3];
  float* out = (float*)d_out;

  const size_t a_elems = (size_t)M_TOTAL * K_TOTAL;  // 67,108,864
  const size_t w_elems = (size_t)N_TOTAL * K_TOTAL;  // 16,777,216
  const size_t need = a_elems + w_elems + (size_t)M_TOTAL * sizeof(float);

  if (ws_size >= need) {
    signed char* A_q = (signed char*)d_ws;
    signed char* W_q = A_q + a_elems;
    float* a_s = (float*)(W_q + w_elems);
    quant_a<<<M_TOTAL, 256, 0, stream>>>(A, (unsigned*)A_q, a_s);
    cvt_w_i8<<<2048, 256, 0, stream>>>(W, (unsigned*)W_q, (int)(w_elems / 4));
    w8a16_gemm_i8<<<1024, 512, 0, stream>>>(A_q, W_q, a_s, scales, bias, out);
  } else {
    size_t total = (size_t)M_TOTAL * N_TOTAL;
    naive_gemm<<<(unsigned)((total + 255) / 256), 256, 0, stream>>>(A, W, scales, bias, out);
  }
}

// Round 12
// 414.636 us; speedup vs baseline: 1.3732x; 1.3732x over previous
//
#include <hip/hip_runtime.h>
#include <hip/hip_bf16.h>

// out[B,S,O] = A[B,S,I] @ W[O,I]^T * scales[O] + bias[O]
// M = 16384, N = 4096, K = 4096. Output fp32.
// i8 path: A per-row quant (amax/127), W exact i8; mfma_i32_16x16x64_i8;
// dequant epilogue acc * (ascale[m]*scales[n]) + bias[n].
// R12: reads-one-phase-ahead on the R7 LDS skeleton. Every QUAD consumes
// operands read >=1 phase earlier; tile-crossing QUAD(1,0)(t-1) runs at P1(t).
// Safety (fixes all three prior failure mechanisms):
//  - tile-t LDS first read at P1(t), after end-P4(t-1) fence+barrier (R8 fix)
//  - every ds_read drained by its QUAD >=1 barrier before region overwrite
//    (stages at P1 / P4 only; b1's region staged P4, after P3 drain) (R5 fix)
//  - sched_barrier(0) at every segment edge pins QUAD clusters (rule 18/19)
//  - b0 double-buffered by parity with STATIC names via 2x unroll (rule 20)
#define M_TOTAL 16384
#define N_TOTAL 4096
#define K_TOTAL 4096
#define NT (K_TOTAL / 128)  // 32 K-tiles of BK=128 (i8)

typedef __attribute__((ext_vector_type(4))) int i32x4;

__device__ __forceinline__ unsigned pack4(int a, int b, int c, int d) {
  return (a & 0xFF) | ((b & 0xFF) << 8) | ((c & 0xFF) << 16) | ((d & 0xFF) << 24);
}

// ---- A quantization: one block per row; lane-contiguous 16B loads ----
__global__ __launch_bounds__(256) void quant_a(const float* __restrict__ A,
                                               unsigned* __restrict__ Aq,
                                               float* __restrict__ ascale) {
  const int row = blockIdx.x;
  const int tid = threadIdx.x;
  const float4* src = reinterpret_cast<const float4*>(A + (size_t)row * K_TOTAL);
  float4 v[4];
#pragma unroll
  for (int c = 0; c < 4; ++c) v[c] = src[tid + 256 * c];
  float amax = 0.0f;
#pragma unroll
  for (int c = 0; c < 4; ++c)
    amax = fmaxf(amax, fmaxf(fmaxf(fabsf(v[c].x), fabsf(v[c].y)),
                             fmaxf(fabsf(v[c].z), fabsf(v[c].w))));
#pragma unroll
  for (int off = 32; off > 0; off >>= 1) amax = fmaxf(amax, __shfl_xor(amax, off, 64));
  __shared__ float wmax[4];
  if ((tid & 63) == 0) wmax[tid >> 6] = amax;
  __syncthreads();
  amax = fmaxf(fmaxf(wmax[0], wmax[1]), fmaxf(wmax[2], wmax[3]));
  amax = fmaxf(amax, 1e-20f);
  const float rs = 127.0f / amax;
  if (tid == 0) ascale[row] = amax * (1.0f / 127.0f);

  unsigned* dst = Aq + (size_t)row * (K_TOTAL / 4);
#pragma unroll
  for (int c = 0; c < 4; ++c) {
    int q[4];
    float f[4] = {v[c].x, v[c].y, v[c].z, v[c].w};
#pragma unroll
    for (int i = 0; i < 4; ++i) {
      int t = (int)rintf(f[i] * rs);
      q[i] = t < -127 ? -127 : (t > 127 ? 127 : t);
    }
    dst[tid + 256 * c] = pack4(q[0], q[1], q[2], q[3]);
  }
}

// ---- W int32 -> int8: one int4 -> one u32 per thread, fully coalesced ----
__global__ void cvt_w_i8(const int* __restrict__ W, unsigned* __restrict__ Wq, int n4) {
  const int stride = gridDim.x * blockDim.x;
  for (int i = blockIdx.x * blockDim.x + threadIdx.x; i < n4; i += stride) {
    int4 v = reinterpret_cast<const int4*>(W)[i];
    Wq[i] = pack4(v.x, v.y, v.z, v.w);
  }
}

// ======== 256x256 i8 GEMM — R7 LDS skeleton, reads-one-phase-ahead ========
#define GLOAD_LDS16(gp, lp)                                                \
  __builtin_amdgcn_global_load_lds(                                        \
      (const __attribute__((address_space(1))) void*)(gp),                 \
      (__attribute__((address_space(3))) void*)(lp), 16, 0, 0)

#define BAR() asm volatile("s_barrier" ::: "memory")
#define VM(n) asm volatile("s_waitcnt vmcnt(" #n ")" ::: "memory")
#define SCHED0() __builtin_amdgcn_sched_barrier(0)

// LDS map (131072 B): buf b at b*65536: A_h0 [0,16K) A_h1 [16K,32K)
// B_h0 [32K,48K) B_h1 [48K,64K). Half-tile = 128 rows x 128 i8, stride 128 B.
// Swizzle: (r,c) at byte r*128 + (c ^ ((r&7)<<4)); gload_lds linear dest with
// pre-inverse-swizzled global source (rule #21).
//
// Per tile t (bsel = t&1; BNEW/BPREV = b0 parity sets):
//  P1: RD af0(t), RD BNEW=b0(t); STAGE_A(nxt,1,t+1)   | QUAD(1,0)<af1,BPREV> (tile t-1)
//  P2: RD af1(t), RD b1(t)                            | QUAD(0,0)<af0,BNEW>
//  P3: (no reads/stages)                              | QUAD(0,1)<af0,b1>
//  P4: STAGE_B(cur,0,t+2) STAGE_B(cur,1,t+2) STAGE_A(cur,0,t+2)
//                                                     | QUAD(1,1)<af1,b1>; VM(6)
// vmcnt ledger: queue at end-P4(t) = [B(t+1)h0, B(t+1)h1, A(t+1)h0 (P4,t-1)=6]
// [A(t+1)h1 (P1,t)=2] [B(t+2)h0,h1, A(t+2)h0 (P4,t)=6] = 14 -> VM(6) drains 8
// oldest = tile t+1 complete. Prologue: tile0 x8 + {B1h0,B1h1,A1h0} x6, VM(6).
// WAR: every region's last ds_read is drained by a QUAD >=1 barrier before
// the region's overwriting STAGE issues (checked region-by-region).

__global__ __launch_bounds__(512, 2) void w8a16_gemm_i8(
    const signed char* __restrict__ A,   // [M][K] i8
    const signed char* __restrict__ Bt,  // [N][K] i8
    const float* __restrict__ ascale,    // [M]
    const float* __restrict__ scales, const float* __restrict__ bias,
    float* __restrict__ C) {
  __shared__ alignas(16) unsigned char lds[131072];

  const int tid = threadIdx.x;
  const int w = tid >> 6, l = tid & 63;
  const int wr = w >> 2, wc = w & 3;  // 2x4 wave grid; per-wave 128x64 output

  const int bid = blockIdx.x;
  const int swz = ((bid & 7) << 7) + (bid >> 3);  // XCD-aware, bijective
  const int bn = swz & 15, bm = swz >> 4;

  // --- staging (pre-inverse-swizzled global source) ---
  const int rowq = tid >> 3;
  const int colb = ((l & 7) ^ (l >> 3)) << 4;
  const signed char* pA = A + (size_t)(bm * 256 + rowq) * K_TOTAL + colb;
  const signed char* pB = Bt + (size_t)(bn * 256 + rowq) * K_TOTAL + colb;
  unsigned char* const ldsp = lds;
  const int woff = w << 10;

#define SDA(b_, h_) (ldsp + (b_) * 65536 + (h_) * 16384 + woff)
#define SDB(b_, h_) (ldsp + (b_) * 65536 + 32768 + (h_) * 16384 + woff)
#define STAGE_A(b_, h_, t_)                                                    \
  do {                                                                         \
    GLOAD_LDS16(pA + (size_t)((h_) * 128) * K_TOTAL + (t_) * 128, SDA(b_, h_));\
    GLOAD_LDS16(pA + (size_t)((h_) * 128 + 64) * K_TOTAL + (t_) * 128,         \
                SDA(b_, h_) + 8192);                                           \
  } while (0)
#define STAGE_B(b_, h_, t_)                                                    \
  do {                                                                         \
    GLOAD_LDS16(pB + (size_t)((h_) * 128) * K_TOTAL + (t_) * 128, SDB(b_, h_));\
    GLOAD_LDS16(pB + (size_t)((h_) * 128 + 64) * K_TOTAL + (t_) * 128,         \
                SDB(b_, h_) + 8192);                                           \
  } while (0)

  const int arow = ((l & 15) << 7) + ((((l >> 4) ^ (l & 7)) & 7) << 4);
  const int bOffC = 32768 + (wc >> 1) * 16384 + (wc & 1) * 8192;

  i32x4 af0[8], af1[8];          // m-half operand sets [fm*2+kk]
  i32x4 b0E[4], b0O[4], b1[4];   // n-half sets; b0 dual-buffered by parity
  i32x4 acc[8][4] = {{}};

#define RD_AF(dst_, mh_, bsel_)                                               \
  do {                                                                        \
    const unsigned char* Ab_ = ldsp + (bsel_) * 65536 + wr * 16384;           \
    _Pragma("unroll") for (int fm = 0; fm < 4; ++fm)                          \
        _Pragma("unroll") for (int kk = 0; kk < 2; ++kk)                      \
            dst_[fm * 2 + kk] = *(const i32x4*)(                              \
                Ab_ + ((mh_) * 4 + fm) * 2048 + (arow ^ (kk << 6)));          \
  } while (0)
#define RD_BH(dst_, nh_, bsel_)                                               \
  do {                                                                        \
    const unsigned char* Bb_ = ldsp + (bsel_) * 65536 + bOffC;                \
    _Pragma("unroll") for (int fn = 0; fn < 2; ++fn)                          \
        _Pragma("unroll") for (int kk = 0; kk < 2; ++kk)                      \
            dst_[fn * 2 + kk] = *(const i32x4*)(                              \
                Bb_ + ((nh_) * 2 + fn) * 2048 + (arow ^ (kk << 6)));          \
  } while (0)
#define QUAD(mh_, nh_, AF_, BF_)                                              \
  do {                                                                        \
    __builtin_amdgcn_s_setprio(1);                                            \
    _Pragma("unroll") for (int m = 0; m < 4; ++m)                             \
        _Pragma("unroll") for (int n = 0; n < 2; ++n)                         \
            _Pragma("unroll") for (int kk = 0; kk < 2; ++kk)                  \
                acc[(mh_) * 4 + m][(nh_) * 2 + n] =                           \
                    __builtin_amdgcn_mfma_i32_16x16x64_i8(                    \
                        AF_[m * 2 + kk], BF_[n * 2 + kk],                     \
                        acc[(mh_) * 4 + m][(nh_) * 2 + n], 0, 0, 0);          \
    __builtin_amdgcn_s_setprio(0);                                            \
  } while (0)

#define TILE_BODY(t_, bsel_, BNEW_, BPREV_, doprev_)                          \
  do {                                                                        \
    /* P1 */                                                                  \
    RD_AF(af0, 0, bsel_);                                                     \
    RD_BH(BNEW_, 0, bsel_);                                                   \
    if ((t_) + 1 < NT) STAGE_A((bsel_) ^ 1, 1, (t_) + 1);                     \
    SCHED0(); BAR();                                                          \
    if (doprev_) QUAD(1, 0, af1, BPREV_);                                     \
    SCHED0(); BAR();                                                          \
    /* P2 */                                                                  \
    RD_AF(af1, 1, bsel_);                                                     \
    RD_BH(b1, 1, bsel_);                                                      \
    SCHED0(); BAR();                                                          \
    QUAD(0, 0, af0, BNEW_);                                                   \
    SCHED0(); BAR();                                                          \
    /* P3 */                                                                  \
    QUAD(0, 1, af0, b1);                                                      \
    SCHED0(); BAR();                                                          \
    /* P4 */                                                                  \
    if ((t_) + 2 < NT) {                                                      \
      STAGE_B(bsel_, 0, (t_) + 2);                                            \
      STAGE_B(bsel_, 1, (t_) + 2);                                            \
      STAGE_A(bsel_, 0, (t_) + 2);                                            \
    }                                                                         \
    SCHED0(); BAR();                                                          \
    QUAD(1, 1, af1, b1);                                                      \
    if ((t_) < NT - 2) { VM(6); } else { VM(0); }                             \
    SCHED0(); BAR();                                                          \
  } while (0)

  // --- prologue: tile0 (8) + B(1)h0,B(1)h1,A(1)h0 (6); VM(6) -> tile0 done ---
  STAGE_A(0, 0, 0); STAGE_A(0, 1, 0); STAGE_B(0, 0, 0); STAGE_B(0, 1, 0);
  STAGE_B(1, 0, 1); STAGE_B(1, 1, 1); STAGE_A(1, 0, 1);
  VM(6);
  BAR();

  // --- main loop, unrolled x2 for static b0 parity names ---
  for (int tt = 0; tt < NT; tt += 2) {
    TILE_BODY(tt, 0, b0E, b0O, (tt > 0));
    TILE_BODY(tt + 1, 1, b0O, b0E, 1);
  }
  // close tile NT-1 (odd parity -> its b0 set is b0O)
  QUAD(1, 0, af1, b0O);

  // --- epilogue: C/D col=lane&15, row=(lane>>4)*4+reg; dequant + bias ---
  const int row0 = bm * 256 + wr * 128 + ((l >> 4) << 2);
  const int col0 = bn * 256 + wc * 64 + (l & 15);
#pragma unroll
  for (int fn = 0; fn < 4; ++fn) {
    const int col = col0 + fn * 16;
    const float sc = scales[col];
    const float bi = bias[col];
#pragma unroll
    for (int fm = 0; fm < 8; ++fm) {
      const int r = row0 + fm * 16;
      float* cp = C + (size_t)r * N_TOTAL + col;
#pragma unroll
      for (int j = 0; j < 4; ++j)
        cp[(size_t)j * N_TOTAL] = fmaf((float)acc[fm][fn][j], ascale[r + j] * sc, bi);
    }
  }
}

// ---- guarded fallback (only if d_ws too small) ----
__global__ void naive_gemm(const float* __restrict__ A, const int* __restrict__ W,
                           const float* __restrict__ scales, const float* __restrict__ bias,
                           float* __restrict__ C) {
  size_t idx = (size_t)blockIdx.x * blockDim.x + threadIdx.x;
  if (idx >= (size_t)M_TOTAL * N_TOTAL) return;
  const int n = (int)(idx % N_TOTAL);
  const size_t m = idx / N_TOTAL;
  const float* a = A + m * (size_t)K_TOTAL;
  const int* w = W + (size_t)n * K_TOTAL;
  float s = 0.f;
  for (int k = 0; k < K_TOTAL; ++k) s = fmaf(a[k], (float)w[k], s);
  C[idx] = fmaf(s, scales[n], bias[n]);
}

extern "C" void kernel_launch(void* const* d_in, const int* in_sizes, int n_in,
                              void* d_out, int out_size, void* d_ws, size_t ws_size,
                              hipStream_t stream) {
  const float* A = (const float*)d_in[0];
  const int* W = (const int*)d_in[1];
  const float* scales = (const float*)d_in[2];
  const float* bias = (const float*)d_in[3];
  float* out = (float*)d_out;

  const size_t a_elems = (size_t)M_TOTAL * K_TOTAL;
  const size_t w_elems = (size_t)N_TOTAL * K_TOTAL;
  const size_t need = a_elems + w_elems + (size_t)M_TOTAL * sizeof(float);

  if (ws_size >= need) {
    signed char* A_q = (signed char*)d_ws;
    signed char* W_q = A_q + a_elems;
    float* a_s = (float*)(W_q + w_elems);
    quant_a<<<M_TOTAL, 256, 0, stream>>>(A, (unsigned*)A_q, a_s);
    cvt_w_i8<<<2048, 256, 0, stream>>>(W, (unsigned*)W_q, (int)(w_elems / 4));
    w8a16_gemm_i8<<<1024, 512, 0, stream>>>(A_q, W_q, a_s, scales, bias, out);
  } else {
    size_t total = (size_t)M_TOTAL * N_TOTAL;
    naive_gemm<<<(unsigned)((total + 255) / 256), 256, 0, stream>>>(A, W, scales, bias, out);
  }
}